// Round 6
// baseline (376.310 us; speedup 1.0000x reference)
//
#include <hip/hip_runtime.h>
#include <math.h>

// ---------------------------------------------------------------------------
// YOLOv5-style loss, 3 layers, fp32.
// R10: cost model (fit over R6/R7/R9): total = F(~140us fill+fixed) +
// ~11us/dispatch-slot + device work. R9 taught: spin-waits with O(1000)
// pollers on one line cost ~100us (coherence-point serialization); barriers
// are only viable at O(100) blocks. New structure: 2 dispatches, 0 memsets.
//  D1 entry (83 blocks, residency guaranteed):
//    A: grid-stride zero winner/cnt/acc/D2-tree (3.2MB)
//    -- 83-block MAGIC-FLAG barrier (init-free: stale flags end at MAGIC2,
//       phase-1 checks ==MAGIC1; per-location total order makes phase-2 safe)
//    B: per-entry CIoU/box/scatter/tcls; ciou+xobj kept in registers
//    -- barrier --
//    C: winner self-check -> obj correction in-registers (iou array GONE)
//  D2 scan (3152 blocks): R8 dense+wave-gated body, no winner/iou reads;
//    arrival-only 64-leaf tree; last root-arriver combines acc -> out.
//    (final_kernel dispatch eliminated; nobody spins.)
// ---------------------------------------------------------------------------

#define EPS 1e-7f
#define BS 16
#define NA 3
#define NC 80

#define LOG2E 1.44269504088896340736f
#define LN2   0.69314718055994530942f

// acc layout (floats at ws+16384): box[3][32] obj[3][32] cls[3][32]
#define ACC_BOX 0
#define ACC_OBJ 96
#define ACC_CLS 192

#define MAGIC1 0x51C00001u
#define MAGIC2 0x51C00002u

struct Layer {
    const float* pred;
    const int*   b;
    const int*   a;
    const int*   gj;
    const int*   gi;
    const int*   tcls;
    const float* tbox;
    const float* anc;
    unsigned int* winner;   // [48*g*g] cells, 0 = empty else entry_idx+1
    unsigned int* cnt;      // [48*g*g] entry multiplicity per cell
    int g;
    int n;
};

struct Args {
    Layer L[3];
    int e_cum0, e_cum1, e_cum2;   // entry prefix sums
    int cum0, cum1;               // D2 block partition
    unsigned* flags;              // D1 barrier flags, 64B stride, NOT zeroed
    unsigned* root;               // D2 arrival root counter
    unsigned* leaf;               // D2 leaf counters, 64B stride
    float*    acc;
    uint4*    zbase;              // zero region: tree+acc+winner+cnt
    int       zvec;
    int       nb1, nb2;
};

// bce_with_logits(x, 0) via HW transcendentals: branchless, ~7 VALU ops
__device__ __forceinline__ float bce0(float x) {
    float t = __builtin_amdgcn_exp2f(-fabsf(x) * LOG2E);   // exp(-|x|)
    return fmaxf(x, 0.f) + LN2 * __builtin_amdgcn_logf(1.f + t);
}

__device__ __forceinline__ float fsigmoid(float x) {
    float e = __builtin_amdgcn_exp2f(-x * LOG2E);
    return __builtin_amdgcn_rcpf(1.f + e);
}

// 64-lane wave sum
__device__ __forceinline__ float wred(float v) {
    #pragma unroll
    for (int o = 32; o > 0; o >>= 1) v += __shfl_down(v, o, 64);
    return v;
}

// reduce two independent sums across a 256-thread block (D2)
__device__ __forceinline__ void block_reduce256_2(float& a, float& b) {
    #pragma unroll
    for (int o = 32; o > 0; o >>= 1) {
        a += __shfl_down(a, o, 64);
        b += __shfl_down(b, o, 64);
    }
    __shared__ float sma[4], smb[4];
    int lane = threadIdx.x & 63;
    int wid  = threadIdx.x >> 6;
    if (lane == 0) { sma[wid] = a; smb[wid] = b; }
    __syncthreads();
    if (threadIdx.x == 0) {
        a = sma[0] + sma[1] + sma[2] + sma[3];
        b = smb[0] + smb[1] + smb[2] + smb[3];
    }
}

// init-free small-grid barrier: block bid release-stores tag to its own
// cacheline-flag; all 256 threads poll the nb flags (one each, tid<nb).
// Stale values from a previous iteration are MAGIC2 (never MAGIC1), and
// phase-2 pollers have already observed MAGIC1 this iteration, so the
// per-location total order of agent-scope atomics forbids fall-through.
__device__ __forceinline__ void magic_bar(unsigned* flags, int nb, unsigned tag) {
    __syncthreads();                        // drain block's prior mem ops
    if (threadIdx.x == 0) {
        __threadfence();                    // release
        __hip_atomic_store(flags + 16 * blockIdx.x, tag, __ATOMIC_RELEASE,
                           __HIP_MEMORY_SCOPE_AGENT);
    }
    int t = (int)threadIdx.x;
    for (;;) {
        unsigned v = (t < nb)
            ? __hip_atomic_load(flags + 16 * t, __ATOMIC_RELAXED,
                                __HIP_MEMORY_SCOPE_AGENT)
            : tag;
        int cnt = __syncthreads_count((int)(v == tag));
        if (cnt == 256) break;
        __builtin_amdgcn_s_sleep(2);
    }
    __threadfence();                        // acquire
}

// --- D1: zero -> entries -> winner-check, all partials via 32-slot atomics -
__global__ void entry_kernel(Args A) {
    const int tid = (int)threadIdx.x;
    const int bid = (int)blockIdx.x;

    // phase A: zero tree + acc + winner + cnt
    {
        uint4 z = make_uint4(0u, 0u, 0u, 0u);
        int nthr = A.nb1 * 256;
        for (int i = bid * 256 + tid; i < A.zvec; i += nthr) A.zbase[i] = z;
    }
    magic_bar(A.flags, A.nb1, MAGIC1);

    // phase B: per-entry math + scatter (one entry per thread)
    int jg = bid * 256 + tid;
    int layer = 0, jj = -1, cell = -1;
    float box_c = 0.f, neg_c = 0.f, ciou = 0.f, xobj = 0.f;
    if (jg < A.e_cum2) {
        int j;
        if (jg < A.e_cum0)      { layer = 0; j = jg; }
        else if (jg < A.e_cum1) { layer = 1; j = jg - A.e_cum0; }
        else                    { layer = 2; j = jg - A.e_cum1; }
        const Layer& L = A.L[layer];
        jj = j;
        int b  = L.b[j],  a  = L.a[j];
        int gy = L.gj[j], gx = L.gi[j];
        int g = L.g, gg = g * g;
        int q = b * NA + a;
        const float* base = L.pred + ((size_t)(q * 85) * gg + (size_t)gy * g + gx);
        float px = base[0];
        float py = base[gg];
        float pw = base[2 * (size_t)gg];
        float ph = base[3 * (size_t)gg];
        xobj     = base[4 * (size_t)gg];
        float cx = 2.f * fsigmoid(px) - 0.5f;
        float cy = 2.f * fsigmoid(py) - 0.5f;
        float sw = 2.f * fsigmoid(pw);
        float sh = 2.f * fsigmoid(ph);
        float bw = sw * sw * L.anc[2 * j];
        float bh = sh * sh * L.anc[2 * j + 1];
        float fg = (float)g;
        float4 tb = *(const float4*)(L.tbox + 4 * j);
        float tx = tb.x * fg - (float)gx;
        float ty = tb.y * fg - (float)gy;
        float tw = tb.z * fg;
        float th = tb.w * fg;
        float b1x1 = cx - bw * 0.5f, b1x2 = cx + bw * 0.5f;
        float b1y1 = cy - bh * 0.5f, b1y2 = cy + bh * 0.5f;
        float b2x1 = tx - tw * 0.5f, b2x2 = tx + tw * 0.5f;
        float b2y1 = ty - th * 0.5f, b2y2 = ty + th * 0.5f;
        float iw = fminf(b1x2, b2x2) - fmaxf(b1x1, b2x1);
        float ih = fminf(b1y2, b2y2) - fmaxf(b1y1, b2y1);
        float inter = fmaxf(iw, 0.f) * fmaxf(ih, 0.f);
        float w1 = b1x2 - b1x1, h1 = b1y2 - b1y1 + EPS;
        float w2 = b2x2 - b2x1, h2 = b2y2 - b2y1 + EPS;
        float uni = w1 * h1 + w2 * h2 - inter + EPS;
        float iou = inter / uni;
        float cw  = fmaxf(b1x2, b2x2) - fminf(b1x1, b2x1);
        float chh = fmaxf(b1y2, b2y2) - fminf(b1y1, b2y1);
        float c2  = cw * cw + chh * chh + EPS;
        float dx = b2x1 + b2x2 - b1x1 - b1x2;
        float dy = b2y1 + b2y2 - b1y1 - b1y2;
        float rho2 = (dx * dx + dy * dy) * 0.25f;
        float dv = atanf(w2 / h2) - atanf(w1 / h1);
        float v = (4.f / (float)(M_PI * M_PI)) * dv * dv;
        float alpha = v / (v - iou + (1.f + EPS));
        ciou = iou - (rho2 / c2 + v * alpha);
        cell = q * gg + gy * g + gx;
        atomicMax(&L.winner[cell], (unsigned int)(j + 1));
        atomicAdd(&L.cnt[cell], 1u);
        box_c = 1.f - ciou;
        // class positive term: bce(x,1) = bce(x,0) - x  -> subtract x[tcls]
        neg_c = base[(size_t)(5 + L.tcls[j]) * gg];
    }
    magic_bar(A.flags, A.nb1, MAGIC2);

    // phase C: winner self-check -> obj correction, all in registers
    float corr = 0.f;
    if (cell >= 0 && A.L[layer].winner[cell] == (unsigned)(jj + 1))
        corr = xobj * fmaxf(ciou, 0.f);

    float qv[9] = {0.f,0.f,0.f, 0.f,0.f,0.f, 0.f,0.f,0.f};
    qv[layer]     = box_c;
    qv[3 + layer] = neg_c;
    qv[6 + layer] = corr;
    #pragma unroll
    for (int k = 0; k < 9; ++k) qv[k] = wred(qv[k]);
    if ((tid & 63) == 0) {
        int slot = ((bid << 2) + (tid >> 6)) & 31;
        #pragma unroll
        for (int l = 0; l < 3; ++l) {
            if (qv[l]     != 0.f) atomicAdd(&A.acc[ACC_BOX + l * 32 + slot],  qv[l]);
            if (qv[3 + l] != 0.f) atomicAdd(&A.acc[ACC_CLS + l * 32 + slot], -qv[3 + l]);
            if (qv[6 + l] != 0.f) atomicAdd(&A.acc[ACC_OBJ + l * 32 + slot], -qv[6 + l]);
        }
    }
}

// --- D2: dense obj + wave-gated cls scan + arrival-only tree + combine -----
__global__ void scan_kernel(Args A, float* out) {
    const int tid = (int)threadIdx.x;
    const int bid = (int)blockIdx.x;
    int lb, layer;
    if (bid < A.cum0)      { layer = 0; lb = bid; }
    else if (bid < A.cum1) { layer = 1; lb = bid - A.cum0; }
    else                   { layer = 2; lb = bid - A.cum1; }
    const Layer L = A.L[layer];
    int gg = L.g * L.g;
    int cells = BS * NA * gg;
    int sb = (cells + 1023) >> 10;       // cell groups per chunk
    int group = lb % sb;
    int chunk = lb / sb;                 // 0..7 -> channels 5+10c..5+10c+10
    int ci = group * 1024 + tid * 4;
    float obj_s = 0.f, cls_s = 0.f;
    if (ci < cells) {
        int q = ci / gg;
        int e = ci - q * gg;
        uint4 c4 = *(const uint4*)(L.cnt + ci);
        const float* pbase = L.pred + (size_t)(q * 85) * gg + e;
        if (chunk == 0) {
            float4 x4 = *(const float4*)(pbase + 4 * (size_t)gg);
            obj_s = bce0(x4.x) + bce0(x4.y) + bce0(x4.z) + bce0(x4.w);
        }
        int act = (int)(c4.x | c4.y | c4.z | c4.w);
        if (__any(act)) {
            float f0 = (float)c4.x, f1 = (float)c4.y;
            float f2 = (float)c4.z, f3 = (float)c4.w;
            const float* p = pbase + (size_t)(5 + 10 * chunk) * gg;
            float s0 = 0.f, s1 = 0.f;
            #pragma unroll
            for (int r = 0; r < 10; r += 2) {
                float4 ya = *(const float4*)(p + (size_t)r * gg);
                float4 yb = *(const float4*)(p + (size_t)(r + 1) * gg);
                s0 += f0 * bce0(ya.x) + f1 * bce0(ya.y)
                    + f2 * bce0(ya.z) + f3 * bce0(ya.w);
                s1 += f0 * bce0(yb.x) + f1 * bce0(yb.y)
                    + f2 * bce0(yb.z) + f3 * bce0(yb.w);
            }
            cls_s = s0 + s1;
        }
    }
    block_reduce256_2(obj_s, cls_s);
    if (tid == 0) {
        int s = bid & 31;
        if (chunk == 0)   atomicAdd(&A.acc[ACC_OBJ + layer * 32 + s], obj_s);
        if (cls_s != 0.f) atomicAdd(&A.acc[ACC_CLS + layer * 32 + s], cls_s);
    }

    // arrival-only tree: 64 leaves; nobody spins; last root-arriver combines
    __syncthreads();                       // drains all waves' mem ops
    __shared__ int lastf;
    if (tid == 0) {
        lastf = 0;
        __threadfence();                   // release my atomics
        int l = bid & 63;
        int nl = (A.nb2 - l + 63) >> 6;    // blocks in leaf l
        unsigned pl = atomicAdd(A.leaf + 16 * l, 1u);
        if ((int)pl == nl - 1) {
            unsigned pr = atomicAdd(A.root, 1u);
            if (pr == 63u) lastf = 1;
        }
    }
    __syncthreads();
    if (!lastf) return;
    __threadfence();                       // acquire everyone's atomics
    __shared__ float part[9];
    if (tid < 9) {
        int l = tid % 3, qn = tid / 3;     // qn: 0=box 1=obj 2=cls
        const float* s = &A.acc[qn * 96 + l * 32];
        float v = 0.f;
        #pragma unroll
        for (int k = 0; k < 32; ++k) v += s[k];
        part[tid] = v;
    }
    __syncthreads();
    if (tid == 0) {
        float n0 = (float)A.L[0].n, n1 = (float)A.L[1].n, n2 = (float)A.L[2].n;
        float c0 = (float)(BS * NA) * (float)(A.L[0].g * A.L[0].g);
        float c1 = (float)(BS * NA) * (float)(A.L[1].g * A.L[1].g);
        float c2 = (float)(BS * NA) * (float)(A.L[2].g * A.L[2].g);
        float box_l = part[0] / n0 + part[1] / n1 + part[2] / n2;
        float obj_l = 0.4f * part[3] / c0 + 1.0f * part[4] / c1
                    + 4.0f * part[5] / c2;
        float cls_l = part[6] / (n0 * NC) + part[7] / (n1 * NC)
                    + part[8] / (n2 * NC);
        out[0] = 0.05f * box_l + 1.0f * obj_l + 0.5f * cls_l;
    }
}

extern "C" void kernel_launch(void* const* d_in, const int* in_sizes, int n_in,
                              void* d_out, int out_size, void* d_ws, size_t ws_size,
                              hipStream_t stream) {
    (void)n_in; (void)out_size; (void)ws_size;
    char* ws = (char*)d_ws;

    // memory map:
    //   [0,     8192)  D1 magic flags (83x64B) -- NEVER zeroed (init-free)
    //   [8192,  8256)  D2 root counter
    //   [8256, 12352)  D2 leaf counters (64x64B)
    //   [16384,17536)  acc: 288 floats
    //   [18432, ...)   winner[i], cnt[i] per layer
    // zero region (D1 phase A): [8192, 18432) + winner/cnt
    Args A;
    int n[3], g[3], cells[3];
    size_t off = 18432;
    size_t winner_off[3], cnt_off[3];

    for (int i = 0; i < 3; ++i) {
        n[i] = in_sizes[8 * i + 1];
        int gg = in_sizes[8 * i] / (BS * 255);
        int gv = (int)(sqrt((double)gg) + 0.5);
        g[i] = gv;
        cells[i] = BS * NA * gv * gv;
        winner_off[i] = off; off += (size_t)cells[i] * 4;
        cnt_off[i]    = off; off += (size_t)cells[i] * 4;
    }
    size_t zero_end = off;

    for (int i = 0; i < 3; ++i) {
        Layer& L = A.L[i];
        L.pred = (const float*)d_in[8 * i + 0];
        L.b    = (const int*)  d_in[8 * i + 1];
        L.a    = (const int*)  d_in[8 * i + 2];
        L.gj   = (const int*)  d_in[8 * i + 3];
        L.gi   = (const int*)  d_in[8 * i + 4];
        L.tbox = (const float*)d_in[8 * i + 5];
        L.tcls = (const int*)  d_in[8 * i + 6];
        L.anc  = (const float*)d_in[8 * i + 7];
        L.winner = (unsigned int*)(ws + winner_off[i]);
        L.cnt    = (unsigned int*)(ws + cnt_off[i]);
        L.g = g[i];
        L.n = n[i];
    }
    int ntot = n[0] + n[1] + n[2];
    A.e_cum0 = n[0];
    A.e_cum1 = n[0] + n[1];
    A.e_cum2 = ntot;
    A.flags = (unsigned*)ws;
    A.root  = (unsigned*)(ws + 8192);
    A.leaf  = (unsigned*)(ws + 8256);
    A.acc   = (float*)(ws + 16384);
    A.zbase = (uint4*)(ws + 8192);
    A.zvec  = (int)((zero_end - 8192) / 16);
    A.nb1   = (ntot + 255) / 256;          // 83 <= 128 flag slots
    int s0 = ((cells[0] + 1023) / 1024) * 8;
    int s1 = ((cells[1] + 1023) / 1024) * 8;
    int s2 = ((cells[2] + 1023) / 1024) * 8;
    A.cum0 = s0; A.cum1 = s0 + s1;
    A.nb2  = s0 + s1 + s2;

    entry_kernel<<<A.nb1, 256, 0, stream>>>(A);
    scan_kernel<<<A.nb2, 256, 0, stream>>>(A, (float*)d_out);
}

// Round 8
// 230.222 us; speedup vs baseline: 1.6346x; 1.6346x over previous
//
#include <hip/hip_runtime.h>
#include <math.h>

// ---------------------------------------------------------------------------
// YOLOv5-style loss, 3 layers, fp32.
// R12 = R11 resubmitted verbatim (R11's bench died on container acquisition,
// not on the kernel; no measurement was taken).
// R11 theory: R10's scan ran 190us vs <62us for the same body in R8 -- the
// added per-block __threadfence() in the arrival tree is the cause: agent-
// scope fences on gfx950 must cross non-coherent per-XCD L2s, emitting L2
// writeback/invalidates; 3152 of them trash L2 for the whole resident grid
// (explains R5's 343 GB/s, R9's 427 GB/s, R10's 370 GB/s scans).
// Fix: FENCE-FREE combine. acc is written ONLY via atomicAdd (coherence-
// point ops), so the handoff needs no cache maintenance:
//   tid0: acc atomicAdds -> s_waitcnt vmcnt(0) (HW completion) ->
//   leaf atomicAdd (use RETURNED value: data-dependency ordering) ->
//   root atomicAdd -> last arriver reads acc via atomicAdd(p, 0.0f)
//   (returning atomic = coherence-point read) and writes out.
// Structure = R8's proven 230us pipeline (memset 3.2MB + entry + scan with
// winner/iou correction in chunk 0) minus the final dispatch.
// ---------------------------------------------------------------------------

#define EPS 1e-7f
#define BS 16
#define NA 3
#define NC 80

#define LOG2E 1.44269504088896340736f
#define LN2   0.69314718055994530942f

// accumulator layout (floats): [0..2]=box  [3..98]=obj 3x32  [99..194]=cls 3x32
#define ACC_OBJ 3
#define ACC_CLS 99
// header bytes: [0,1024) acc; [1024,1088) root; [1088,5184) leaf 64x64B; pad to 8192
#define HDR_BYTES 8192

struct Layer {
    const float* pred;
    const int*   b;
    const int*   a;
    const int*   gj;
    const int*   gi;
    const int*   tcls;
    const float* tbox;
    const float* anc;
    unsigned int* winner;   // [48*g*g] cells, 0 = empty else entry_idx+1
    unsigned int* cnt;      // [48*g*g] entry multiplicity per cell
    float*        iou;      // [n] CIoU per entry
    int g;
    int n;
};

struct Args {
    Layer L[3];
    int cum0;   // block-partition boundaries for the current launch
    int cum1;
    unsigned* root;   // arrival root counter
    unsigned* leaf;   // 64 leaf counters, 64B stride
    int nb2;          // scan grid size
};

__device__ __forceinline__ int pick_layer(const Args& A, int& lb) {
    int bid = blockIdx.x;
    if (bid < A.cum0) { lb = bid; return 0; }
    if (bid < A.cum1) { lb = bid - A.cum0; return 1; }
    lb = bid - A.cum1; return 2;
}

// reduce two independent sums across a 256-thread block
__device__ __forceinline__ void block_reduce256_2(float& a, float& b) {
    #pragma unroll
    for (int o = 32; o > 0; o >>= 1) {
        a += __shfl_down(a, o, 64);
        b += __shfl_down(b, o, 64);
    }
    __shared__ float sma[4], smb[4];
    int lane = threadIdx.x & 63;
    int wid  = threadIdx.x >> 6;
    if (lane == 0) { sma[wid] = a; smb[wid] = b; }
    __syncthreads();
    if (threadIdx.x == 0) {
        a = sma[0] + sma[1] + sma[2] + sma[3];
        b = smb[0] + smb[1] + smb[2] + smb[3];
    }
}

// bce_with_logits(x, 0) via HW transcendentals: branchless, ~7 VALU ops
__device__ __forceinline__ float bce0(float x) {
    float t = __builtin_amdgcn_exp2f(-fabsf(x) * LOG2E);   // exp(-|x|)
    return fmaxf(x, 0.f) + LN2 * __builtin_amdgcn_logf(1.f + t);
}

// sigmoid via HW exp2 + rcp
__device__ __forceinline__ float fsigmoid(float x) {
    float e = __builtin_amdgcn_exp2f(-x * LOG2E);
    return __builtin_amdgcn_rcpf(1.f + e);
}

// --- kernel 1: per-entry CIoU + box loss + winner/cnt scatter + tcls gather -
__global__ void entry_kernel(Args A, float* acc) {
    int lb; int layer = pick_layer(A, lb);
    const Layer L = A.L[layer];
    int j = lb * 256 + (int)threadIdx.x;
    float box_c = 0.f;
    float neg_c = 0.f;    // x[tcls] to subtract from cls sum
    if (j < L.n) {
        int b  = L.b[j],  a  = L.a[j];
        int gy = L.gj[j], gx = L.gi[j];
        int g = L.g, gg = g * g;
        int q = b * NA + a;
        const float* base = L.pred + ((size_t)(q * 85) * gg + (size_t)gy * g + gx);
        float px = base[0];
        float py = base[gg];
        float pw = base[2 * (size_t)gg];
        float ph = base[3 * (size_t)gg];
        // decode
        float cx = 2.f * fsigmoid(px) - 0.5f;
        float cy = 2.f * fsigmoid(py) - 0.5f;
        float sw = 2.f * fsigmoid(pw);
        float sh = 2.f * fsigmoid(ph);
        float bw = sw * sw * L.anc[2 * j];
        float bh = sh * sh * L.anc[2 * j + 1];
        float fg = (float)g;
        float4 tb = *(const float4*)(L.tbox + 4 * j);
        float tx = tb.x * fg - (float)gx;
        float ty = tb.y * fg - (float)gy;
        float tw = tb.z * fg;
        float th = tb.w * fg;
        // CIoU
        float b1x1 = cx - bw * 0.5f, b1x2 = cx + bw * 0.5f;
        float b1y1 = cy - bh * 0.5f, b1y2 = cy + bh * 0.5f;
        float b2x1 = tx - tw * 0.5f, b2x2 = tx + tw * 0.5f;
        float b2y1 = ty - th * 0.5f, b2y2 = ty + th * 0.5f;
        float iw = fminf(b1x2, b2x2) - fmaxf(b1x1, b2x1);
        float ih = fminf(b1y2, b2y2) - fmaxf(b1y1, b2y1);
        float inter = fmaxf(iw, 0.f) * fmaxf(ih, 0.f);
        float w1 = b1x2 - b1x1, h1 = b1y2 - b1y1 + EPS;
        float w2 = b2x2 - b2x1, h2 = b2y2 - b2y1 + EPS;
        float uni = w1 * h1 + w2 * h2 - inter + EPS;
        float iou = inter / uni;
        float cw  = fmaxf(b1x2, b2x2) - fminf(b1x1, b2x1);
        float chh = fmaxf(b1y2, b2y2) - fminf(b1y1, b2y1);
        float c2  = cw * cw + chh * chh + EPS;
        float dx = b2x1 + b2x2 - b1x1 - b1x2;
        float dy = b2y1 + b2y2 - b1y1 - b1y2;
        float rho2 = (dx * dx + dy * dy) * 0.25f;
        float dv = atanf(w2 / h2) - atanf(w1 / h1);
        float v = (4.f / (float)(M_PI * M_PI)) * dv * dv;
        float alpha = v / (v - iou + (1.f + EPS));
        float ciou = iou - (rho2 / c2 + v * alpha);
        L.iou[j] = ciou;
        int cell = q * gg + gy * g + gx;
        atomicMax(&L.winner[cell], (unsigned int)(j + 1));
        atomicAdd(&L.cnt[cell], 1u);
        box_c = 1.f - ciou;
        // class positive term: bce(x,1) = bce(x,0) - x  -> subtract x[tcls]
        neg_c = base[(size_t)(5 + L.tcls[j]) * gg];
    }
    block_reduce256_2(box_c, neg_c);
    if (threadIdx.x == 0) {
        atomicAdd(&acc[layer], box_c);
        atomicAdd(&acc[ACC_CLS + layer * 32 + (blockIdx.x & 31)], -neg_c);
    }
}

// --- kernel 2: DENSE wave-gated scan + fence-free tree combine -------------
__global__ void scan_kernel(Args A, float* acc, float* out) {
    const int tid = (int)threadIdx.x;
    const int bid = (int)blockIdx.x;
    int lb; int layer = pick_layer(A, lb);
    const Layer L = A.L[layer];
    int gg = L.g * L.g;
    int cells = BS * NA * gg;
    int sb = (cells + 1023) >> 10;       // cell groups per chunk
    int group = lb % sb;                 // consecutive blocks -> consecutive groups
    int chunk = lb / sb;                 // 0..7, channels 5+10c .. 5+10c+10
    int ci = group * 1024 + tid * 4;
    float obj_s = 0.f, cls_s = 0.f;
    if (ci < cells) {
        int q = ci / gg;
        int e = ci - q * gg;
        uint4 c4 = *(const uint4*)(L.cnt + ci);
        const float* pbase = L.pred + (size_t)(q * 85) * gg + e;
        if (chunk == 0) {
            uint4 w4 = *(const uint4*)(L.winner + ci);
            float4 x4 = *(const float4*)(pbase + 4 * (size_t)gg);
            obj_s = bce0(x4.x) + bce0(x4.y) + bce0(x4.z) + bce0(x4.w);
            if (w4.x) obj_s -= x4.x * fmaxf(L.iou[w4.x - 1], 0.f);
            if (w4.y) obj_s -= x4.y * fmaxf(L.iou[w4.y - 1], 0.f);
            if (w4.z) obj_s -= x4.z * fmaxf(L.iou[w4.z - 1], 0.f);
            if (w4.w) obj_s -= x4.w * fmaxf(L.iou[w4.w - 1], 0.f);
        }
        // per-WAVE gate: skip the class loop only if the whole wave's
        // 256-cell span is inactive (keeps loads coalesced when active)
        int act = (int)(c4.x | c4.y | c4.z | c4.w);
        if (__any(act)) {
            float f0 = (float)c4.x, f1 = (float)c4.y;
            float f2 = (float)c4.z, f3 = (float)c4.w;
            const float* p = pbase + (size_t)(5 + 10 * chunk) * gg;
            float s0 = 0.f, s1 = 0.f;
            #pragma unroll
            for (int r = 0; r < 10; r += 2) {
                float4 ya = *(const float4*)(p + (size_t)r * gg);
                float4 yb = *(const float4*)(p + (size_t)(r + 1) * gg);
                s0 += f0 * bce0(ya.x) + f1 * bce0(ya.y)
                    + f2 * bce0(ya.z) + f3 * bce0(ya.w);
                s1 += f0 * bce0(yb.x) + f1 * bce0(yb.y)
                    + f2 * bce0(yb.z) + f3 * bce0(yb.w);
            }
            cls_s = s0 + s1;
        }
    }
    block_reduce256_2(obj_s, cls_s);

    // partial-sum publication + FENCE-FREE arrival tree (no __threadfence
    // anywhere: acc is atomic-only data, ordered by HW completion + data
    // dependencies on returned atomic values)
    __shared__ int lastf;
    if (tid == 0) {
        lastf = 0;
        int s = bid & 31;
        if (chunk == 0)   atomicAdd(&acc[ACC_OBJ + layer * 32 + s], obj_s);
        if (cls_s != 0.f) atomicAdd(&acc[ACC_CLS + layer * 32 + s], cls_s);
        asm volatile("s_waitcnt vmcnt(0)" ::: "memory");  // acc adds COMPLETE
        int l = bid & 63;
        int nl = (A.nb2 - l + 63) >> 6;                   // blocks in leaf l
        unsigned pl = atomicAdd(A.leaf + 16 * l, 1u);     // returned -> dep chain
        if ((int)pl == nl - 1) {
            unsigned pr = atomicAdd(A.root, 1u);
            if (pr == 63u) lastf = 1;
        }
    }
    __syncthreads();
    if (!lastf) return;

    // last arriver: read acc via RETURNING atomics (coherence-point reads),
    // reduce 195 slots -> 9 sums in LDS, combine, write out.
    __shared__ float part[9];
    if (tid < 9) part[tid] = 0.f;
    __syncthreads();
    if (tid < 195) {
        float v = atomicAdd(&acc[tid], 0.0f);
        int pi = (tid < 3) ? tid
               : (tid < 99 ? 3 + (tid - 3) / 32 : 6 + (tid - 99) / 32);
        atomicAdd(&part[pi], v);              // LDS atomic
    }
    __syncthreads();
    if (tid == 0) {
        float n0 = (float)A.L[0].n, n1 = (float)A.L[1].n, n2 = (float)A.L[2].n;
        float c0 = (float)(BS * NA) * (float)(A.L[0].g * A.L[0].g);
        float c1 = (float)(BS * NA) * (float)(A.L[1].g * A.L[1].g);
        float c2 = (float)(BS * NA) * (float)(A.L[2].g * A.L[2].g);
        float box_l = part[0] / n0 + part[1] / n1 + part[2] / n2;
        float obj_l = 0.4f * part[3] / c0 + 1.0f * part[4] / c1
                    + 4.0f * part[5] / c2;
        float cls_l = part[6] / (n0 * NC) + part[7] / (n1 * NC)
                    + part[8] / (n2 * NC);
        out[0] = 0.05f * box_l + 1.0f * obj_l + 0.5f * cls_l;
    }
}

extern "C" void kernel_launch(void* const* d_in, const int* in_sizes, int n_in,
                              void* d_out, int out_size, void* d_ws, size_t ws_size,
                              hipStream_t stream) {
    (void)n_in; (void)out_size; (void)ws_size;
    char* ws = (char*)d_ws;

    Args A;
    int n[3], g[3], cells[3];
    size_t off = HDR_BYTES;                // header: acc + root + leaf
    size_t winner_off[3], cnt_off[3], iou_off[3];

    for (int i = 0; i < 3; ++i) {
        n[i] = in_sizes[8 * i + 1];
        int gg = in_sizes[8 * i] / (BS * 255);
        int gv = (int)(sqrt((double)gg) + 0.5);
        g[i] = gv;
        cells[i] = BS * NA * gv * gv;
        winner_off[i] = off; off += (size_t)cells[i] * 4;
        cnt_off[i]    = off; off += (size_t)cells[i] * 4;
    }
    size_t zero_bytes = off;               // header + winner + cnt
    for (int i = 0; i < 3; ++i) { iou_off[i] = off; off += (size_t)n[i] * 4; }

    for (int i = 0; i < 3; ++i) {
        Layer& L = A.L[i];
        L.pred = (const float*)d_in[8 * i + 0];
        L.b    = (const int*)  d_in[8 * i + 1];
        L.a    = (const int*)  d_in[8 * i + 2];
        L.gj   = (const int*)  d_in[8 * i + 3];
        L.gi   = (const int*)  d_in[8 * i + 4];
        L.tbox = (const float*)d_in[8 * i + 5];
        L.tcls = (const int*)  d_in[8 * i + 6];
        L.anc  = (const float*)d_in[8 * i + 7];
        L.winner = (unsigned int*)(ws + winner_off[i]);
        L.cnt    = (unsigned int*)(ws + cnt_off[i]);
        L.iou    = (float*)(ws + iou_off[i]);
        L.g = g[i];
        L.n = n[i];
    }
    float* acc = (float*)ws;
    A.root = (unsigned*)(ws + 1024);
    A.leaf = (unsigned*)(ws + 1088);

    hipMemsetAsync(d_ws, 0, zero_bytes, stream);

    // entry kernel: CIoU + scatter winner/cnt + tcls gather
    {
        int b0 = (n[0] + 255) / 256, b1 = (n[1] + 255) / 256, b2 = (n[2] + 255) / 256;
        A.cum0 = b0; A.cum1 = b0 + b1;
        entry_kernel<<<b0 + b1 + b2, 256, 0, stream>>>(A, acc);
    }
    // dense scan: (cell-group x 8 channel-chunks) blocks per layer,
    // ends with fence-free tree combine + out write (no final dispatch)
    {
        int s0 = ((cells[0] + 1023) / 1024) * 8;
        int s1 = ((cells[1] + 1023) / 1024) * 8;
        int s2 = ((cells[2] + 1023) / 1024) * 8;
        A.cum0 = s0; A.cum1 = s0 + s1;
        A.nb2  = s0 + s1 + s2;
        scan_kernel<<<A.nb2, 256, 0, stream>>>(A, acc, (float*)d_out);
    }
}